// Round 2
// baseline (323.154 us; speedup 1.0000x reference)
//
#include <hip/hip_runtime.h>
#include <hip/hip_bf16.h>
#include <stdint.h>

#define BB 8
#define CC 512
#define KK 512
#define NN 4096

typedef __bf16 bf16x8 __attribute__((ext_vector_type(8)));
typedef float f32x4 __attribute__((ext_vector_type(4)));
typedef __attribute__((address_space(3))) uint8_t* lds_ptr_t;
typedef const __attribute__((address_space(1))) uint8_t* gbl_ptr_t;

static __device__ __forceinline__ unsigned short bf16_bits(float f) {
    __bf16 h = (__bf16)f;
    return __builtin_bit_cast(unsigned short, h);
}

// ---------------------------------------------------------------------------
// P1: fp32 -> bf16 hi/lo split (hi = RN(f), lo = RN(f - hi)); vectorized.
// ---------------------------------------------------------------------------
__global__ void __launch_bounds__(256) split_hi_lo(const float* __restrict__ in,
        unsigned short* __restrict__ hi, unsigned short* __restrict__ lo, int n4) {
    int idx = blockIdx.x * blockDim.x + threadIdx.x;
    int stride = gridDim.x * blockDim.x;
    const float4* in4 = (const float4*)in;
    ushort4* h4 = (ushort4*)hi;
    ushort4* l4 = (ushort4*)lo;
    for (int i = idx; i < n4; i += stride) {
        float4 v = in4[i];
        float a[4] = {v.x, v.y, v.z, v.w};
        unsigned short hb[4], lb[4];
        #pragma unroll
        for (int j = 0; j < 4; ++j) {
            __bf16 h = (__bf16)a[j];
            float hf = (float)h;
            __bf16 l = (__bf16)(a[j] - hf);
            hb[j] = __builtin_bit_cast(unsigned short, h);
            lb[j] = __builtin_bit_cast(unsigned short, l);
        }
        h4[i] = make_ushort4(hb[0], hb[1], hb[2], hb[3]);
        l4[i] = make_ushort4(lb[0], lb[1], lb[2], lb[3]);
    }
}

// ---------------------------------------------------------------------------
// K1: energy[b][c][k] = sum_n x[b][c][n]*y[b][k][n], split-bf16 (3 MFMAs).
// 64x64 output tile, BK=64, split-N=2 (each block does 2048 of the 4096
// contraction, writing its own partial-energy buffer; softmax sums them).
// Staging: global_load_lds width 16, linear LDS dest + XOR-swizzled source;
// ds_read_b128 fragments with the same swizzle (G21 both-sides involution).
// ---------------------------------------------------------------------------
__global__ void __launch_bounds__(256) energy_gemm(
        const unsigned short* __restrict__ xh, const unsigned short* __restrict__ xl,
        const unsigned short* __restrict__ yh, const unsigned short* __restrict__ yl,
        float* __restrict__ energy) {
    __shared__ __align__(16) uint8_t smem[4 * 8192];  // Ah, Al, Bh, Bl : [64][64] bf16
    const int ktile = blockIdx.x;        // 0..7  (key tiles)
    const int ctile = blockIdx.y;        // 0..7  (query tiles)
    const int b = blockIdx.z >> 1;
    const int half = blockIdx.z & 1;     // split-N half
    const int t = threadIdx.x;
    const int wave = t >> 6, lane = t & 63;

    const size_t rowB = (size_t)NN * 2;  // 8192 B per bf16 row
    const uint8_t* srcBase[4];
    srcBase[0] = (const uint8_t*)xh + ((size_t)b * CC + ctile * 64) * rowB + (size_t)half * 4096;
    srcBase[1] = (const uint8_t*)xl + ((size_t)b * CC + ctile * 64) * rowB + (size_t)half * 4096;
    srcBase[2] = (const uint8_t*)yh + ((size_t)b * KK + ktile * 64) * rowB + (size_t)half * 4096;
    srcBase[3] = (const uint8_t*)yl + ((size_t)b * KK + ktile * 64) * rowB + (size_t)half * 4096;

    f32x4 acc[2][2] = {};
    const int waveRow = wave >> 1, waveCol = wave & 1;

    for (int step = 0; step < 32; ++step) {
        const size_t colByte = (size_t)step * 128;
        #pragma unroll
        for (int i = 0; i < 8; ++i) {
            // c = i*4+wave in 0..31; tile = c>>3 = i>>1 (compile-time), lc = (i&1)*4+wave
            const int tile = i >> 1;
            const int lc = (i & 1) * 4 + wave;      // chunk 0..7 within tile
            const int u = lc * 64 + lane;           // 16B unit index in tile
            const int r = u >> 3;                   // row 0..63
            const int c3 = (u & 7) ^ (r & 7);       // inverse-swizzled source unit
            const uint8_t* src = srcBase[tile] + (size_t)r * rowB + colByte + c3 * 16;
            __builtin_amdgcn_global_load_lds((gbl_ptr_t)src,
                (lds_ptr_t)(smem + tile * 8192 + lc * 1024), 16, 0, 0);
        }
        __syncthreads();
        #pragma unroll
        for (int kf = 0; kf < 2; ++kf) {
            bf16x8 fah[2], fal[2], fbh[2], fbl[2];
            #pragma unroll
            for (int m = 0; m < 2; ++m) {
                int r = waveRow * 32 + m * 16 + (lane & 15);
                int c3 = (kf * 4 + (lane >> 4)) ^ (r & 7);
                fah[m] = *(const bf16x8*)(smem + 0 * 8192 + r * 128 + c3 * 16);
                fal[m] = *(const bf16x8*)(smem + 1 * 8192 + r * 128 + c3 * 16);
            }
            #pragma unroll
            for (int n = 0; n < 2; ++n) {
                int r = waveCol * 32 + n * 16 + (lane & 15);
                int c3 = (kf * 4 + (lane >> 4)) ^ (r & 7);
                fbh[n] = *(const bf16x8*)(smem + 2 * 8192 + r * 128 + c3 * 16);
                fbl[n] = *(const bf16x8*)(smem + 3 * 8192 + r * 128 + c3 * 16);
            }
            #pragma unroll
            for (int m = 0; m < 2; ++m)
            #pragma unroll
            for (int n = 0; n < 2; ++n) {
                acc[m][n] = __builtin_amdgcn_mfma_f32_16x16x32_bf16(fah[m], fbh[n], acc[m][n], 0, 0, 0);
                acc[m][n] = __builtin_amdgcn_mfma_f32_16x16x32_bf16(fah[m], fbl[n], acc[m][n], 0, 0, 0);
                acc[m][n] = __builtin_amdgcn_mfma_f32_16x16x32_bf16(fal[m], fbh[n], acc[m][n], 0, 0, 0);
            }
        }
        __syncthreads();
    }

    // C/D layout: col = lane&15, row = (lane>>4)*4 + reg  [m89-verified]
    float* eout = energy + (size_t)half * BB * CC * KK + (size_t)b * CC * KK;
    const int row0 = ctile * 64 + waveRow * 32;
    const int col0 = ktile * 64 + waveCol * 32;
    #pragma unroll
    for (int m = 0; m < 2; ++m)
    #pragma unroll
    for (int n = 0; n < 2; ++n)
    #pragma unroll
    for (int j = 0; j < 4; ++j) {
        int rr = row0 + m * 16 + (lane >> 4) * 4 + j;
        int cc2 = col0 + n * 16 + (lane & 15);
        eout[(size_t)rr * KK + cc2] = acc[m][n][j];
    }
}

// ---------------------------------------------------------------------------
// K2: inverted softmax. softmax(max-e) == exp(min-e)/sum. One wave per row,
// sums the two split-N partial energies. Writes bf16 attention.
// ---------------------------------------------------------------------------
__global__ void __launch_bounds__(256) softmax_inv(
        const float* __restrict__ e0, const float* __restrict__ e1,
        unsigned short* __restrict__ att) {
    const int t = threadIdx.x;
    const int wave = t >> 6, lane = t & 63;
    const int row = blockIdx.x * 4 + wave;   // 0..B*C-1
    const float* p0 = e0 + (size_t)row * KK;
    const float* p1 = e1 + (size_t)row * KK;
    float v[8];
    float mn = 3.0e38f;
    #pragma unroll
    for (int i = 0; i < 8; ++i) {
        v[i] = p0[lane + i * 64] + p1[lane + i * 64];
        mn = fminf(mn, v[i]);
    }
    #pragma unroll
    for (int off = 32; off > 0; off >>= 1) mn = fminf(mn, __shfl_xor(mn, off));
    float p[8]; float s = 0.f;
    #pragma unroll
    for (int i = 0; i < 8; ++i) { p[i] = __expf(mn - v[i]); s += p[i]; }
    #pragma unroll
    for (int off = 32; off > 0; off >>= 1) s += __shfl_xor(s, off);
    float inv = 1.0f / s;
    unsigned short* arow = att + (size_t)row * KK;
    #pragma unroll
    for (int i = 0; i < 8; ++i) arow[lane + i * 64] = bf16_bits(p[i] * inv);
}

// ---------------------------------------------------------------------------
// P2: yT[b][n][k] = yh[b][k][n] (bf16), 64x64 LDS tile, pad 66 (conflict-free).
// ---------------------------------------------------------------------------
__global__ void __launch_bounds__(256) transpose_bf16(
        const unsigned short* __restrict__ yh, unsigned short* __restrict__ yT) {
    __shared__ unsigned short tile[64][66];
    const int n0 = blockIdx.x * 64, k0 = blockIdx.y * 64, b = blockIdx.z;
    const int t = threadIdx.x;
    const unsigned short* src = yh + (size_t)b * KK * NN;
    unsigned short* dst = yT + (size_t)b * NN * KK;
    #pragma unroll
    for (int i = 0; i < 2; ++i) {
        int idx = t + 256 * i;      // 0..511 (16B vec units)
        int r = idx >> 3;           // 0..63 (k)
        int c8 = (idx & 7) * 8;     // 0..56 (n)
        uint4 v = *(const uint4*)(src + (size_t)(k0 + r) * NN + n0 + c8);
        unsigned int w[4] = {v.x, v.y, v.z, v.w};
        #pragma unroll
        for (int q = 0; q < 4; ++q) {
            tile[r][c8 + 2 * q]     = (unsigned short)(w[q] & 0xffffu);
            tile[r][c8 + 2 * q + 1] = (unsigned short)(w[q] >> 16);
        }
    }
    __syncthreads();
    #pragma unroll
    for (int i = 0; i < 16; ++i) {
        int idx = t + 256 * i;     // 0..4095
        int rn = idx >> 6;         // 0..63 (n)
        int ck = idx & 63;         // 0..63 (k)
        dst[(size_t)(n0 + rn) * KK + k0 + ck] = tile[ck][rn];
    }
}

// ---------------------------------------------------------------------------
// K3: out[b][c][n] = x[b][c][n] + scale * sum_k att[b][c][k]*yT[b][n][k].
// 128x128 tile, BK=64, 8 k-steps; same swizzled global_load_lds staging.
// ---------------------------------------------------------------------------
__global__ void __launch_bounds__(256) pv_residual(
        const unsigned short* __restrict__ att, const unsigned short* __restrict__ yT,
        const float* __restrict__ x, const float* __restrict__ scale,
        float* __restrict__ out) {
    __shared__ __align__(16) uint8_t smem[2 * 16384];   // A: att [128][64], B: yT [128][64]
    const int ntile = blockIdx.x;   // 0..31
    const int ctile = blockIdx.y;   // 0..3
    const int b = blockIdx.z;
    const int t = threadIdx.x;
    const int wave = t >> 6, lane = t & 63;
    const size_t rowB = (size_t)KK * 2;   // 1024 B
    const uint8_t* srcA = (const uint8_t*)att + ((size_t)b * CC + ctile * 128) * rowB;
    const uint8_t* srcB = (const uint8_t*)yT  + ((size_t)b * NN + ntile * 128) * rowB;

    f32x4 acc[4][4] = {};
    const int waveRow = wave >> 1, waveCol = wave & 1;

    for (int step = 0; step < 8; ++step) {
        const size_t colByte = (size_t)step * 128;
        #pragma unroll
        for (int i = 0; i < 8; ++i) {
            const uint8_t* base = (i < 4) ? srcA : srcB;  // compile-time per unrolled i
            const int tile = i >> 2;
            const int lc = (i & 3) * 4 + wave;            // 0..15
            const int u = lc * 64 + lane;
            const int r = u >> 3;                         // 0..127
            const int c3 = (u & 7) ^ (r & 7);
            const uint8_t* src = base + (size_t)r * rowB + colByte + c3 * 16;
            __builtin_amdgcn_global_load_lds((gbl_ptr_t)src,
                (lds_ptr_t)(smem + tile * 16384 + lc * 1024), 16, 0, 0);
        }
        __syncthreads();
        #pragma unroll
        for (int kf = 0; kf < 2; ++kf) {
            bf16x8 fa[4], fb[4];
            #pragma unroll
            for (int m = 0; m < 4; ++m) {
                int r = waveRow * 64 + m * 16 + (lane & 15);
                int c3 = (kf * 4 + (lane >> 4)) ^ (r & 7);
                fa[m] = *(const bf16x8*)(smem + r * 128 + c3 * 16);
            }
            #pragma unroll
            for (int n = 0; n < 4; ++n) {
                int r = waveCol * 64 + n * 16 + (lane & 15);
                int c3 = (kf * 4 + (lane >> 4)) ^ (r & 7);
                fb[n] = *(const bf16x8*)(smem + 16384 + r * 128 + c3 * 16);
            }
            #pragma unroll
            for (int m = 0; m < 4; ++m)
            #pragma unroll
            for (int n = 0; n < 4; ++n)
                acc[m][n] = __builtin_amdgcn_mfma_f32_16x16x32_bf16(fa[m], fb[n], acc[m][n], 0, 0, 0);
        }
        __syncthreads();
    }

    const float s = scale[0];
    const int row0 = ctile * 128 + waveRow * 64;
    const int col0 = ntile * 128 + waveCol * 64;
    #pragma unroll
    for (int m = 0; m < 4; ++m)
    #pragma unroll
    for (int n = 0; n < 4; ++n)
    #pragma unroll
    for (int j = 0; j < 4; ++j) {
        int rr = row0 + m * 16 + (lane >> 4) * 4 + j;
        int cc2 = col0 + n * 16 + (lane & 15);
        size_t idx = ((size_t)b * CC + rr) * NN + cc2;
        out[idx] = x[idx] + s * acc[m][n][j];
    }
}

// ---------------------------------------------------------------------------
// Workspace layout (peak 144 MB):
//   [0,32M)    xh            -> reused as yT after energy_gemm
//   [32M,64M)  xl            -> reused as att after energy_gemm
//   [64M,96M)  yh
//   [96M,128M) yl
//   [128M,144M) energy partials (2 x 8 MB)
// ---------------------------------------------------------------------------
extern "C" void kernel_launch(void* const* d_in, const int* in_sizes, int n_in,
                              void* d_out, int out_size, void* d_ws, size_t ws_size,
                              hipStream_t stream) {
    const float* x = (const float*)d_in[0];
    const float* y = (const float*)d_in[1];
    const float* scale = (const float*)d_in[2];
    float* out = (float*)d_out;
    uint8_t* ws = (uint8_t*)d_ws;
    const size_t MB = 1024 * 1024;
    unsigned short* xh = (unsigned short*)(ws + 0 * MB);
    unsigned short* xl = (unsigned short*)(ws + 32 * MB);
    unsigned short* yh = (unsigned short*)(ws + 64 * MB);
    unsigned short* yl = (unsigned short*)(ws + 96 * MB);
    float* energy = (float*)(ws + 128 * MB);
    unsigned short* yT  = (unsigned short*)(ws + 0 * MB);   // alias xh (dead)
    unsigned short* att = (unsigned short*)(ws + 32 * MB);  // alias xl (dead)

    const int n4 = BB * CC * NN / 4;
    split_hi_lo<<<4096, 256, 0, stream>>>(x, xh, xl, n4);
    split_hi_lo<<<4096, 256, 0, stream>>>(y, yh, yl, n4);
    energy_gemm<<<dim3(8, 8, BB * 2), 256, 0, stream>>>(xh, xl, yh, yl, energy);
    transpose_bf16<<<dim3(NN / 64, KK / 64, BB), 256, 0, stream>>>(yh, yT);
    softmax_inv<<<dim3(BB * CC / 4), 256, 0, stream>>>(
        energy, energy + (size_t)BB * CC * KK, att);
    pv_residual<<<dim3(NN / 128, CC / 128, BB), 256, 0, stream>>>(att, yT, x, scale, out);
}

// Round 3
// 302.299 us; speedup vs baseline: 1.0690x; 1.0690x over previous
//
#include <hip/hip_runtime.h>
#include <hip/hip_bf16.h>
#include <stdint.h>

#define BB 8
#define CC 512
#define KK 512
#define NN 4096

typedef __bf16 bf16x8 __attribute__((ext_vector_type(8)));
typedef float f32x4 __attribute__((ext_vector_type(4)));
typedef __attribute__((address_space(3))) uint8_t* lds_ptr_t;
typedef const __attribute__((address_space(1))) uint8_t* gbl_ptr_t;

static __device__ __forceinline__ unsigned short bf16_bits(float f) {
    __bf16 h = (__bf16)f;
    return __builtin_bit_cast(unsigned short, h);
}

// ---------------------------------------------------------------------------
// P1: fp32 -> bf16 hi/lo split (hi = RN(f), lo = RN(f - hi)); vectorized.
// ---------------------------------------------------------------------------
__global__ void __launch_bounds__(256) split_hi_lo(const float* __restrict__ in,
        unsigned short* __restrict__ hi, unsigned short* __restrict__ lo, int n4) {
    int idx = blockIdx.x * blockDim.x + threadIdx.x;
    int stride = gridDim.x * blockDim.x;
    const float4* in4 = (const float4*)in;
    ushort4* h4 = (ushort4*)hi;
    ushort4* l4 = (ushort4*)lo;
    for (int i = idx; i < n4; i += stride) {
        float4 v = in4[i];
        float a[4] = {v.x, v.y, v.z, v.w};
        unsigned short hb[4], lb[4];
        #pragma unroll
        for (int j = 0; j < 4; ++j) {
            __bf16 h = (__bf16)a[j];
            float hf = (float)h;
            __bf16 l = (__bf16)(a[j] - hf);
            hb[j] = __builtin_bit_cast(unsigned short, h);
            lb[j] = __builtin_bit_cast(unsigned short, l);
        }
        h4[i] = make_ushort4(hb[0], hb[1], hb[2], hb[3]);
        l4[i] = make_ushort4(lb[0], lb[1], lb[2], lb[3]);
    }
}

// ---------------------------------------------------------------------------
// K1: energy[b][c][k] = sum_n x[b][c][n]*y[b][k][n], split-bf16 (3 MFMAs).
// 128x128 output tile, BK=64, split-N=4 (each block does 1024 of the 4096
// contraction, 16 K-steps, writing one of 4 partial buffers living in d_out).
// Staging: global_load_lds width 16, linear LDS dest + XOR-swizzled source;
// ds_read_b128 fragments with the same swizzle (G21 both-sides involution).
// Grid (4,4,32) = 512 blocks = 2/CU resident (LDS 64 KB), 4 waves (2x2),
// each wave owns a 64x64 quadrant: 96 MFMA : 32 ds_read_b128 per K-step.
// ---------------------------------------------------------------------------
__global__ void __launch_bounds__(256) energy_gemm(
        const unsigned short* __restrict__ xh, const unsigned short* __restrict__ xl,
        const unsigned short* __restrict__ yh, const unsigned short* __restrict__ yl,
        float* __restrict__ epart) {
    __shared__ __align__(16) uint8_t smem[4 * 16384];  // Ah, Al, Bh, Bl : [128][64] bf16
    const int ktile = blockIdx.x;        // 0..3  (key tiles, 128 each)
    const int ctile = blockIdx.y;        // 0..3  (query tiles, 128 each)
    const int b = blockIdx.z >> 2;
    const int quarter = blockIdx.z & 3;  // split-N quarter (1024 contraction cols)
    const int t = threadIdx.x;
    const int wave = t >> 6, lane = t & 63;

    const size_t rowB = (size_t)NN * 2;  // 8192 B per bf16 row
    const uint8_t* srcBase[4];
    srcBase[0] = (const uint8_t*)xh + ((size_t)b * CC + ctile * 128) * rowB + (size_t)quarter * 2048;
    srcBase[1] = (const uint8_t*)xl + ((size_t)b * CC + ctile * 128) * rowB + (size_t)quarter * 2048;
    srcBase[2] = (const uint8_t*)yh + ((size_t)b * KK + ktile * 128) * rowB + (size_t)quarter * 2048;
    srcBase[3] = (const uint8_t*)yl + ((size_t)b * KK + ktile * 128) * rowB + (size_t)quarter * 2048;

    f32x4 acc[4][4] = {};
    const int waveRow = wave >> 1, waveCol = wave & 1;

    for (int step = 0; step < 16; ++step) {
        const size_t colByte = (size_t)step * 128;
        #pragma unroll
        for (int i = 0; i < 16; ++i) {
            const int tile = i >> 2;                // compile-time after unroll
            const int lc = (i & 3) * 4 + wave;      // chunk 0..15 within tile
            const int u = lc * 64 + lane;           // 16B unit index in tile
            const int r = u >> 3;                   // row 0..127
            const int c3 = (u & 7) ^ (r & 7);       // inverse-swizzled source unit
            const uint8_t* src = srcBase[tile] + (size_t)r * rowB + colByte + c3 * 16;
            __builtin_amdgcn_global_load_lds((gbl_ptr_t)src,
                (lds_ptr_t)(smem + tile * 16384 + lc * 1024), 16, 0, 0);
        }
        __syncthreads();
        #pragma unroll
        for (int kf = 0; kf < 2; ++kf) {
            bf16x8 fah[4], fal[4], fbh[4], fbl[4];
            #pragma unroll
            for (int m = 0; m < 4; ++m) {
                int r = waveRow * 64 + m * 16 + (lane & 15);
                int c3 = (kf * 4 + (lane >> 4)) ^ (r & 7);
                fah[m] = *(const bf16x8*)(smem + 0 * 16384 + r * 128 + c3 * 16);
                fal[m] = *(const bf16x8*)(smem + 1 * 16384 + r * 128 + c3 * 16);
            }
            #pragma unroll
            for (int n = 0; n < 4; ++n) {
                int r = waveCol * 64 + n * 16 + (lane & 15);
                int c3 = (kf * 4 + (lane >> 4)) ^ (r & 7);
                fbh[n] = *(const bf16x8*)(smem + 2 * 16384 + r * 128 + c3 * 16);
                fbl[n] = *(const bf16x8*)(smem + 3 * 16384 + r * 128 + c3 * 16);
            }
            #pragma unroll
            for (int m = 0; m < 4; ++m)
            #pragma unroll
            for (int n = 0; n < 4; ++n) {
                acc[m][n] = __builtin_amdgcn_mfma_f32_16x16x32_bf16(fah[m], fbh[n], acc[m][n], 0, 0, 0);
                acc[m][n] = __builtin_amdgcn_mfma_f32_16x16x32_bf16(fah[m], fbl[n], acc[m][n], 0, 0, 0);
                acc[m][n] = __builtin_amdgcn_mfma_f32_16x16x32_bf16(fal[m], fbh[n], acc[m][n], 0, 0, 0);
            }
        }
        __syncthreads();
    }

    // C/D layout: col = lane&15, row = (lane>>4)*4 + reg  [m89-verified]
    float* eout = epart + (size_t)quarter * BB * CC * KK + (size_t)b * CC * KK;
    const int row0 = ctile * 128 + waveRow * 64;
    const int col0 = ktile * 128 + waveCol * 64;
    #pragma unroll
    for (int m = 0; m < 4; ++m)
    #pragma unroll
    for (int n = 0; n < 4; ++n)
    #pragma unroll
    for (int j = 0; j < 4; ++j) {
        int rr = row0 + m * 16 + (lane >> 4) * 4 + j;
        int cc2 = col0 + n * 16 + (lane & 15);
        eout[(size_t)rr * KK + cc2] = acc[m][n][j];
    }
}

// ---------------------------------------------------------------------------
// K2: inverted softmax. softmax(max-e) == exp(min-e)/sum. One wave per row,
// sums the four split-N partial energies (living in d_out). Writes bf16 att.
// ---------------------------------------------------------------------------
__global__ void __launch_bounds__(256) softmax_inv(
        const float* __restrict__ e, unsigned short* __restrict__ att) {
    const int t = threadIdx.x;
    const int wave = t >> 6, lane = t & 63;
    const int row = blockIdx.x * 4 + wave;   // 0..B*C-1
    const size_t Q = (size_t)BB * CC * KK;
    const float* p0 = e + (size_t)row * KK;
    float v[8];
    float mn = 3.0e38f;
    #pragma unroll
    for (int i = 0; i < 8; ++i) {
        int c = lane + i * 64;
        v[i] = p0[c] + p0[Q + c] + p0[2 * Q + c] + p0[3 * Q + c];
        mn = fminf(mn, v[i]);
    }
    #pragma unroll
    for (int off = 32; off > 0; off >>= 1) mn = fminf(mn, __shfl_xor(mn, off));
    float p[8]; float s = 0.f;
    #pragma unroll
    for (int i = 0; i < 8; ++i) { p[i] = __expf(mn - v[i]); s += p[i]; }
    #pragma unroll
    for (int off = 32; off > 0; off >>= 1) s += __shfl_xor(s, off);
    float inv = 1.0f / s;
    unsigned short* arow = att + (size_t)row * KK;
    #pragma unroll
    for (int i = 0; i < 8; ++i) arow[lane + i * 64] = bf16_bits(p[i] * inv);
}

// ---------------------------------------------------------------------------
// P2: yT[b][n][k] = yh[b][k][n] (bf16), 64x64 LDS tile, pad 66 (conflict-free).
// ---------------------------------------------------------------------------
__global__ void __launch_bounds__(256) transpose_bf16(
        const unsigned short* __restrict__ yh, unsigned short* __restrict__ yT) {
    __shared__ unsigned short tile[64][66];
    const int n0 = blockIdx.x * 64, k0 = blockIdx.y * 64, b = blockIdx.z;
    const int t = threadIdx.x;
    const unsigned short* src = yh + (size_t)b * KK * NN;
    unsigned short* dst = yT + (size_t)b * NN * KK;
    #pragma unroll
    for (int i = 0; i < 2; ++i) {
        int idx = t + 256 * i;      // 0..511 (16B vec units)
        int r = idx >> 3;           // 0..63 (k)
        int c8 = (idx & 7) * 8;     // 0..56 (n)
        uint4 v = *(const uint4*)(src + (size_t)(k0 + r) * NN + n0 + c8);
        unsigned int w[4] = {v.x, v.y, v.z, v.w};
        #pragma unroll
        for (int q = 0; q < 4; ++q) {
            tile[r][c8 + 2 * q]     = (unsigned short)(w[q] & 0xffffu);
            tile[r][c8 + 2 * q + 1] = (unsigned short)(w[q] >> 16);
        }
    }
    __syncthreads();
    #pragma unroll
    for (int i = 0; i < 16; ++i) {
        int idx = t + 256 * i;     // 0..4095
        int rn = idx >> 6;         // 0..63 (n)
        int ck = idx & 63;         // 0..63 (k)
        dst[(size_t)(n0 + rn) * KK + k0 + ck] = tile[ck][rn];
    }
}

// ---------------------------------------------------------------------------
// K3: out[b][c][n] = x[b][c][n] + scale * sum_k att[b][c][k]*yT[b][n][k].
// 128x128 tile, BK=64, 8 k-steps; same swizzled global_load_lds staging.
// ---------------------------------------------------------------------------
__global__ void __launch_bounds__(256) pv_residual(
        const unsigned short* __restrict__ att, const unsigned short* __restrict__ yT,
        const float* __restrict__ x, const float* __restrict__ scale,
        float* __restrict__ out) {
    __shared__ __align__(16) uint8_t smem[2 * 16384];   // A: att [128][64], B: yT [128][64]
    const int ntile = blockIdx.x;   // 0..31
    const int ctile = blockIdx.y;   // 0..3
    const int b = blockIdx.z;
    const int t = threadIdx.x;
    const int wave = t >> 6, lane = t & 63;
    const size_t rowB = (size_t)KK * 2;   // 1024 B
    const uint8_t* srcA = (const uint8_t*)att + ((size_t)b * CC + ctile * 128) * rowB;
    const uint8_t* srcB = (const uint8_t*)yT  + ((size_t)b * NN + ntile * 128) * rowB;

    f32x4 acc[4][4] = {};
    const int waveRow = wave >> 1, waveCol = wave & 1;

    for (int step = 0; step < 8; ++step) {
        const size_t colByte = (size_t)step * 128;
        #pragma unroll
        for (int i = 0; i < 8; ++i) {
            const uint8_t* base = (i < 4) ? srcA : srcB;  // compile-time per unrolled i
            const int tile = i >> 2;
            const int lc = (i & 3) * 4 + wave;            // 0..15
            const int u = lc * 64 + lane;
            const int r = u >> 3;                         // 0..127
            const int c3 = (u & 7) ^ (r & 7);
            const uint8_t* src = base + (size_t)r * rowB + colByte + c3 * 16;
            __builtin_amdgcn_global_load_lds((gbl_ptr_t)src,
                (lds_ptr_t)(smem + tile * 16384 + lc * 1024), 16, 0, 0);
        }
        __syncthreads();
        #pragma unroll
        for (int kf = 0; kf < 2; ++kf) {
            bf16x8 fa[4], fb[4];
            #pragma unroll
            for (int m = 0; m < 4; ++m) {
                int r = waveRow * 64 + m * 16 + (lane & 15);
                int c3 = (kf * 4 + (lane >> 4)) ^ (r & 7);
                fa[m] = *(const bf16x8*)(smem + r * 128 + c3 * 16);
            }
            #pragma unroll
            for (int n = 0; n < 4; ++n) {
                int r = waveCol * 64 + n * 16 + (lane & 15);
                int c3 = (kf * 4 + (lane >> 4)) ^ (r & 7);
                fb[n] = *(const bf16x8*)(smem + 16384 + r * 128 + c3 * 16);
            }
            #pragma unroll
            for (int m = 0; m < 4; ++m)
            #pragma unroll
            for (int n = 0; n < 4; ++n)
                acc[m][n] = __builtin_amdgcn_mfma_f32_16x16x32_bf16(fa[m], fb[n], acc[m][n], 0, 0, 0);
        }
        __syncthreads();
    }

    const float s = scale[0];
    const int row0 = ctile * 128 + waveRow * 64;
    const int col0 = ntile * 128 + waveCol * 64;
    #pragma unroll
    for (int m = 0; m < 4; ++m)
    #pragma unroll
    for (int n = 0; n < 4; ++n)
    #pragma unroll
    for (int j = 0; j < 4; ++j) {
        int rr = row0 + m * 16 + (lane >> 4) * 4 + j;
        int cc2 = col0 + n * 16 + (lane & 15);
        size_t idx = ((size_t)b * CC + rr) * NN + cc2;
        out[idx] = x[idx] + s * acc[m][n][j];
    }
}

// ---------------------------------------------------------------------------
// Workspace layout (132 MB of ws + d_out reused as scratch):
//   ws[0,32M)    xh        -> reused as yT after energy_gemm
//   ws[32M,64M)  xl        -> reused as att after energy_gemm
//   ws[64M,96M)  yh
//   ws[96M,128M) yl
//   d_out[0,32M) 4 x 8 MB energy partials (dead once softmax_inv reads them;
//                pv_residual overwrites d_out at the end)
// ---------------------------------------------------------------------------
extern "C" void kernel_launch(void* const* d_in, const int* in_sizes, int n_in,
                              void* d_out, int out_size, void* d_ws, size_t ws_size,
                              hipStream_t stream) {
    const float* x = (const float*)d_in[0];
    const float* y = (const float*)d_in[1];
    const float* scale = (const float*)d_in[2];
    float* out = (float*)d_out;
    uint8_t* ws = (uint8_t*)d_ws;
    const size_t MB = 1024 * 1024;
    unsigned short* xh = (unsigned short*)(ws + 0 * MB);
    unsigned short* xl = (unsigned short*)(ws + 32 * MB);
    unsigned short* yh = (unsigned short*)(ws + 64 * MB);
    unsigned short* yl = (unsigned short*)(ws + 96 * MB);
    float* epart = out;                                     // d_out as scratch
    unsigned short* yT  = (unsigned short*)(ws + 0 * MB);   // alias xh (dead)
    unsigned short* att = (unsigned short*)(ws + 32 * MB);  // alias xl (dead)

    const int n4 = BB * CC * NN / 4;
    split_hi_lo<<<4096, 256, 0, stream>>>(x, xh, xl, n4);
    split_hi_lo<<<4096, 256, 0, stream>>>(y, yh, yl, n4);
    energy_gemm<<<dim3(4, 4, BB * 4), 256, 0, stream>>>(xh, xl, yh, yl, epart);
    transpose_bf16<<<dim3(NN / 64, KK / 64, BB), 256, 0, stream>>>(yh, yT);
    softmax_inv<<<dim3(BB * CC / 4), 256, 0, stream>>>(epart, att);
    pv_residual<<<dim3(NN / 128, CC / 128, BB), 256, 0, stream>>>(att, yT, x, scale, out);
}

// Round 5
// 294.141 us; speedup vs baseline: 1.0986x; 1.0277x over previous
//
#include <hip/hip_runtime.h>
#include <hip/hip_bf16.h>
#include <stdint.h>

#define BB 8
#define CC 512
#define KK 512
#define NN 4096

typedef __bf16 bf16x8 __attribute__((ext_vector_type(8)));
typedef float f32x4 __attribute__((ext_vector_type(4)));
typedef __attribute__((address_space(3))) uint8_t* lds_ptr_t;
typedef const __attribute__((address_space(1))) uint8_t* gbl_ptr_t;

static __device__ __forceinline__ unsigned short bf16_bits(float f) {
    __bf16 h = (__bf16)f;
    return __builtin_bit_cast(unsigned short, h);
}

// ---------------------------------------------------------------------------
// P1: fp32 -> bf16 hi/lo split (hi = RN(f), lo = RN(f - hi)); vectorized.
// ---------------------------------------------------------------------------
__global__ void __launch_bounds__(256) split_hi_lo(const float* __restrict__ in,
        unsigned short* __restrict__ hi, unsigned short* __restrict__ lo, int n4) {
    int idx = blockIdx.x * blockDim.x + threadIdx.x;
    int stride = gridDim.x * blockDim.x;
    const float4* in4 = (const float4*)in;
    ushort4* h4 = (ushort4*)hi;
    ushort4* l4 = (ushort4*)lo;
    for (int i = idx; i < n4; i += stride) {
        float4 v = in4[i];
        float a[4] = {v.x, v.y, v.z, v.w};
        unsigned short hb[4], lb[4];
        #pragma unroll
        for (int j = 0; j < 4; ++j) {
            __bf16 h = (__bf16)a[j];
            float hf = (float)h;
            __bf16 l = (__bf16)(a[j] - hf);
            hb[j] = __builtin_bit_cast(unsigned short, h);
            lb[j] = __builtin_bit_cast(unsigned short, l);
        }
        h4[i] = make_ushort4(hb[0], hb[1], hb[2], hb[3]);
        l4[i] = make_ushort4(lb[0], lb[1], lb[2], lb[3]);
    }
}

// ---------------------------------------------------------------------------
// P2: y fp32 -> yh, yl (bf16, [k][n]) AND yT (= yh transposed, [n][k]).
// One read of y replaces the old separate y-split + transpose kernels.
// 64x64 tile per block; LDS pad 66 keeps the transposed read conflict-free.
// ---------------------------------------------------------------------------
__global__ void __launch_bounds__(256) split_y_T(const float* __restrict__ y,
        unsigned short* __restrict__ yh, unsigned short* __restrict__ yl,
        unsigned short* __restrict__ yT) {
    __shared__ unsigned short tile[64][66];
    const int n0 = blockIdx.x * 64, k0 = blockIdx.y * 64, b = blockIdx.z;
    const int t = threadIdx.x;
    const float* src = y + (size_t)b * KK * NN;
    unsigned short* dsth = yh + (size_t)b * KK * NN;
    unsigned short* dstl = yl + (size_t)b * KK * NN;
    unsigned short* dstT = yT + (size_t)b * NN * KK;
    #pragma unroll
    for (int i = 0; i < 4; ++i) {
        int idx = t + 256 * i;      // 0..1023 float4 units
        int r = idx >> 4;           // 0..63 (k)
        int c4 = (idx & 15) * 4;    // 0..60 (n)
        float4 v = *(const float4*)(src + (size_t)(k0 + r) * NN + n0 + c4);
        float a[4] = {v.x, v.y, v.z, v.w};
        unsigned short hb[4], lb[4];
        #pragma unroll
        for (int q = 0; q < 4; ++q) {
            __bf16 h = (__bf16)a[q];
            float hf = (float)h;
            __bf16 l = (__bf16)(a[q] - hf);
            hb[q] = __builtin_bit_cast(unsigned short, h);
            lb[q] = __builtin_bit_cast(unsigned short, l);
            tile[r][c4 + q] = hb[q];
        }
        size_t off = (size_t)(k0 + r) * NN + n0 + c4;
        *(ushort4*)(dsth + off) = make_ushort4(hb[0], hb[1], hb[2], hb[3]);
        *(ushort4*)(dstl + off) = make_ushort4(lb[0], lb[1], lb[2], lb[3]);
    }
    __syncthreads();
    #pragma unroll
    for (int i = 0; i < 16; ++i) {
        int idx = t + 256 * i;     // 0..4095
        int rn = idx >> 6;         // 0..63 (n)
        int ck = idx & 63;         // 0..63 (k)
        dstT[(size_t)(n0 + rn) * KK + k0 + ck] = tile[ck][rn];
    }
}

// ---------------------------------------------------------------------------
// K1: energy[b][c][k] = sum_n x[b][c][n]*y[b][k][n], split-bf16 (3 MFMAs).
// 128x128 output tile, BK=64, split-N=4. 1D grid 512 with bijective XCD
// swizzle: dispatch slot j -> XCD j%8; decode so each XCD owns 4 complete
// (b,quarter) slices (16 MiB = L2-resident) -> FETCH ~ unique data.
// Staging: global_load_lds width 16, linear LDS dest + XOR-swizzled source;
// ds_read_b128 fragments with the same swizzle (G21 both-sides involution).
// ---------------------------------------------------------------------------
__global__ void __launch_bounds__(256) energy_gemm(
        const unsigned short* __restrict__ xh, const unsigned short* __restrict__ xl,
        const unsigned short* __restrict__ yh, const unsigned short* __restrict__ yl,
        float* __restrict__ epart) {
    __shared__ __align__(16) uint8_t smem[4 * 16384];  // Ah, Al, Bh, Bl : [128][64] bf16
    // XCD-aware decode: j = xcd + 8*(ktile + 4*ctile + 16*sgrp)
    const int j = blockIdx.x;
    const int xcd = j & 7;
    const int rem = j >> 3;              // 0..63
    const int ktile = rem & 3;           // 0..3  (key tiles, 128 each)
    const int ctile = (rem >> 2) & 3;    // 0..3  (query tiles, 128 each)
    const int sgrp = rem >> 4;           // 0..3
    const int slice = xcd + 8 * sgrp;    // 0..31
    const int b = slice >> 2;
    const int quarter = slice & 3;       // split-N quarter (1024 contraction cols)
    const int t = threadIdx.x;
    const int wave = t >> 6, lane = t & 63;

    const size_t rowB = (size_t)NN * 2;  // 8192 B per bf16 row
    const uint8_t* srcBase[4];
    srcBase[0] = (const uint8_t*)xh + ((size_t)b * CC + ctile * 128) * rowB + (size_t)quarter * 2048;
    srcBase[1] = (const uint8_t*)xl + ((size_t)b * CC + ctile * 128) * rowB + (size_t)quarter * 2048;
    srcBase[2] = (const uint8_t*)yh + ((size_t)b * KK + ktile * 128) * rowB + (size_t)quarter * 2048;
    srcBase[3] = (const uint8_t*)yl + ((size_t)b * KK + ktile * 128) * rowB + (size_t)quarter * 2048;

    f32x4 acc[4][4] = {};
    const int waveRow = wave >> 1, waveCol = wave & 1;

    for (int step = 0; step < 16; ++step) {
        const size_t colByte = (size_t)step * 128;
        #pragma unroll
        for (int i = 0; i < 16; ++i) {
            const int tile = i >> 2;                // compile-time after unroll
            const int lc = (i & 3) * 4 + wave;      // chunk 0..15 within tile
            const int u = lc * 64 + lane;           // 16B unit index in tile
            const int r = u >> 3;                   // row 0..127
            const int c3 = (u & 7) ^ (r & 7);       // inverse-swizzled source unit
            const uint8_t* src = srcBase[tile] + (size_t)r * rowB + colByte + c3 * 16;
            __builtin_amdgcn_global_load_lds((gbl_ptr_t)src,
                (lds_ptr_t)(smem + tile * 16384 + lc * 1024), 16, 0, 0);
        }
        __syncthreads();
        #pragma unroll
        for (int kf = 0; kf < 2; ++kf) {
            bf16x8 fah[4], fal[4], fbh[4], fbl[4];
            #pragma unroll
            for (int m = 0; m < 4; ++m) {
                int r = waveRow * 64 + m * 16 + (lane & 15);
                int c3 = (kf * 4 + (lane >> 4)) ^ (r & 7);
                fah[m] = *(const bf16x8*)(smem + 0 * 16384 + r * 128 + c3 * 16);
                fal[m] = *(const bf16x8*)(smem + 1 * 16384 + r * 128 + c3 * 16);
            }
            #pragma unroll
            for (int n = 0; n < 4; ++n) {
                int r = waveCol * 64 + n * 16 + (lane & 15);
                int c3 = (kf * 4 + (lane >> 4)) ^ (r & 7);
                fbh[n] = *(const bf16x8*)(smem + 2 * 16384 + r * 128 + c3 * 16);
                fbl[n] = *(const bf16x8*)(smem + 3 * 16384 + r * 128 + c3 * 16);
            }
            #pragma unroll
            for (int m = 0; m < 4; ++m)
            #pragma unroll
            for (int n = 0; n < 4; ++n) {
                acc[m][n] = __builtin_amdgcn_mfma_f32_16x16x32_bf16(fah[m], fbh[n], acc[m][n], 0, 0, 0);
                acc[m][n] = __builtin_amdgcn_mfma_f32_16x16x32_bf16(fah[m], fbl[n], acc[m][n], 0, 0, 0);
                acc[m][n] = __builtin_amdgcn_mfma_f32_16x16x32_bf16(fal[m], fbh[n], acc[m][n], 0, 0, 0);
            }
        }
        __syncthreads();
    }

    // C/D layout: col = lane&15, row = (lane>>4)*4 + reg  [m89-verified]
    float* eout = epart + (size_t)quarter * BB * CC * KK + (size_t)b * CC * KK;
    const int row0 = ctile * 128 + waveRow * 64;
    const int col0 = ktile * 128 + waveCol * 64;
    #pragma unroll
    for (int m = 0; m < 4; ++m)
    #pragma unroll
    for (int n = 0; n < 4; ++n)
    #pragma unroll
    for (int jj = 0; jj < 4; ++jj) {
        int rr = row0 + m * 16 + (lane >> 4) * 4 + jj;
        int cc2 = col0 + n * 16 + (lane & 15);
        eout[(size_t)rr * KK + cc2] = acc[m][n][jj];
    }
}

// ---------------------------------------------------------------------------
// K2: inverted softmax. softmax(max-e) == exp(min-e)/sum. One wave per row,
// sums the four split-N partial energies (living in d_out). Writes bf16 att.
// ---------------------------------------------------------------------------
__global__ void __launch_bounds__(256) softmax_inv(
        const float* __restrict__ e, unsigned short* __restrict__ att) {
    const int t = threadIdx.x;
    const int wave = t >> 6, lane = t & 63;
    const int row = blockIdx.x * 4 + wave;   // 0..B*C-1
    const size_t Q = (size_t)BB * CC * KK;
    const float* p0 = e + (size_t)row * KK;
    float v[8];
    float mn = 3.0e38f;
    #pragma unroll
    for (int i = 0; i < 8; ++i) {
        int c = lane + i * 64;
        v[i] = p0[c] + p0[Q + c] + p0[2 * Q + c] + p0[3 * Q + c];
        mn = fminf(mn, v[i]);
    }
    #pragma unroll
    for (int off = 32; off > 0; off >>= 1) mn = fminf(mn, __shfl_xor(mn, off));
    float p[8]; float s = 0.f;
    #pragma unroll
    for (int i = 0; i < 8; ++i) { p[i] = __expf(mn - v[i]); s += p[i]; }
    #pragma unroll
    for (int off = 32; off > 0; off >>= 1) s += __shfl_xor(s, off);
    float inv = 1.0f / s;
    unsigned short* arow = att + (size_t)row * KK;
    #pragma unroll
    for (int i = 0; i < 8; ++i) arow[lane + i * 64] = bf16_bits(p[i] * inv);
}

// ---------------------------------------------------------------------------
// K3: out[b][c][n] = x[b][c][n] + scale * sum_k att[b][c][k]*yT[b][n][k].
// 128x128 tile, BK=64, 8 k-steps; same swizzled global_load_lds staging.
// 1D grid 1024, XCD = batch b -> yT/att b-slice (4.5 MiB) L2-resident.
// ---------------------------------------------------------------------------
__global__ void __launch_bounds__(256) pv_residual(
        const unsigned short* __restrict__ att, const unsigned short* __restrict__ yT,
        const float* __restrict__ x, const float* __restrict__ scale,
        float* __restrict__ out) {
    __shared__ __align__(16) uint8_t smem[2 * 16384];   // A: att [128][64], B: yT [128][64]
    const int j = blockIdx.x;
    const int b = j & 7;                 // XCD = batch
    const int rem2 = j >> 3;             // 0..127
    const int ntile = rem2 & 31;         // 0..31
    const int ctile = rem2 >> 5;         // 0..3
    const int t = threadIdx.x;
    const int wave = t >> 6, lane = t & 63;
    const size_t rowB = (size_t)KK * 2;   // 1024 B
    const uint8_t* srcA = (const uint8_t*)att + ((size_t)b * CC + ctile * 128) * rowB;
    const uint8_t* srcB = (const uint8_t*)yT  + ((size_t)b * NN + ntile * 128) * rowB;

    f32x4 acc[4][4] = {};
    const int waveRow = wave >> 1, waveCol = wave & 1;

    for (int step = 0; step < 8; ++step) {
        const size_t colByte = (size_t)step * 128;
        #pragma unroll
        for (int i = 0; i < 8; ++i) {
            const uint8_t* base = (i < 4) ? srcA : srcB;  // compile-time per unrolled i
            const int tile = i >> 2;
            const int lc = (i & 3) * 4 + wave;            // 0..15
            const int u = lc * 64 + lane;
            const int r = u >> 3;                         // 0..127
            const int c3 = (u & 7) ^ (r & 7);
            const uint8_t* src = base + (size_t)r * rowB + colByte + c3 * 16;
            __builtin_amdgcn_global_load_lds((gbl_ptr_t)src,
                (lds_ptr_t)(smem + tile * 16384 + lc * 1024), 16, 0, 0);
        }
        __syncthreads();
        #pragma unroll
        for (int kf = 0; kf < 2; ++kf) {
            bf16x8 fa[4], fb[4];
            #pragma unroll
            for (int m = 0; m < 4; ++m) {
                int r = waveRow * 64 + m * 16 + (lane & 15);
                int c3 = (kf * 4 + (lane >> 4)) ^ (r & 7);
                fa[m] = *(const bf16x8*)(smem + r * 128 + c3 * 16);
            }
            #pragma unroll
            for (int n = 0; n < 4; ++n) {
                int r = waveCol * 64 + n * 16 + (lane & 15);
                int c3 = (kf * 4 + (lane >> 4)) ^ (r & 7);
                fb[n] = *(const bf16x8*)(smem + 16384 + r * 128 + c3 * 16);
            }
            #pragma unroll
            for (int m = 0; m < 4; ++m)
            #pragma unroll
            for (int n = 0; n < 4; ++n)
                acc[m][n] = __builtin_amdgcn_mfma_f32_16x16x32_bf16(fa[m], fb[n], acc[m][n], 0, 0, 0);
        }
        __syncthreads();
    }

    const float s = scale[0];
    const int row0 = ctile * 128 + waveRow * 64;
    const int col0 = ntile * 128 + waveCol * 64;
    #pragma unroll
    for (int m = 0; m < 4; ++m)
    #pragma unroll
    for (int n = 0; n < 4; ++n)
    #pragma unroll
    for (int jj = 0; jj < 4; ++jj) {
        int rr = row0 + m * 16 + (lane >> 4) * 4 + jj;
        int cc2 = col0 + n * 16 + (lane & 15);
        size_t idx = ((size_t)b * CC + rr) * NN + cc2;
        out[idx] = x[idx] + s * acc[m][n][jj];
    }
}

// ---------------------------------------------------------------------------
// Buffer plan (ws 132 MiB; d_out doubles as scratch):
//   ws[0,32M)    xh
//   ws[32M,64M)  yh
//   ws[64M,96M)  yl
//   ws[96M,128M) yT
//   ws[128M,132M) att
//   d_out[0,32M)  4 x 8 MiB energy partials  (dead after softmax_inv)
//   d_out[32M,64M) xl                        (dead after energy_gemm)
//   pv_residual finally overwrites all of d_out.
// ---------------------------------------------------------------------------
extern "C" void kernel_launch(void* const* d_in, const int* in_sizes, int n_in,
                              void* d_out, int out_size, void* d_ws, size_t ws_size,
                              hipStream_t stream) {
    const float* x = (const float*)d_in[0];
    const float* y = (const float*)d_in[1];
    const float* scale = (const float*)d_in[2];
    float* out = (float*)d_out;
    uint8_t* ws = (uint8_t*)d_ws;
    uint8_t* ob = (uint8_t*)d_out;
    const size_t MB = 1024 * 1024;
    unsigned short* xh = (unsigned short*)(ws + 0 * MB);
    unsigned short* yh = (unsigned short*)(ws + 32 * MB);
    unsigned short* yl = (unsigned short*)(ws + 64 * MB);
    unsigned short* yT = (unsigned short*)(ws + 96 * MB);
    unsigned short* att = (unsigned short*)(ws + 128 * MB);
    float* epart = (float*)(ob + 0 * MB);                  // d_out lower half
    unsigned short* xl = (unsigned short*)(ob + 32 * MB);  // d_out upper half

    const int n4 = BB * CC * NN / 4;
    split_hi_lo<<<4096, 256, 0, stream>>>(x, xh, xl, n4);
    split_y_T<<<dim3(NN / 64, KK / 64, BB), 256, 0, stream>>>(y, yh, yl, yT);
    energy_gemm<<<512, 256, 0, stream>>>(xh, xl, yh, yl, epart);
    softmax_inv<<<BB * CC / 4, 256, 0, stream>>>(epart, att);
    pv_residual<<<1024, 256, 0, stream>>>(att, yT, x, scale, out);
}

// Round 6
// 290.583 us; speedup vs baseline: 1.1121x; 1.0122x over previous
//
#include <hip/hip_runtime.h>
#include <hip/hip_bf16.h>
#include <stdint.h>

#define BB 8
#define CC 512
#define KK 512
#define NN 4096

typedef __bf16 bf16x8 __attribute__((ext_vector_type(8)));
typedef float f32x4 __attribute__((ext_vector_type(4)));
typedef __attribute__((address_space(3))) uint8_t* lds_ptr_t;
typedef const __attribute__((address_space(1))) uint8_t* gbl_ptr_t;

static __device__ __forceinline__ unsigned short bf16_bits(float f) {
    __bf16 h = (__bf16)f;
    return __builtin_bit_cast(unsigned short, h);
}

// ---------------------------------------------------------------------------
// P1 (merged): z<8  -> y-branch: y fp32 -> yh, yl ([k][n]) + yT ([n][k])
//              z>=8 -> x-branch: x fp32 -> xh, xl (no transpose)
// Both operate on a 64x64 tile; y-branch uses padded LDS for the transpose.
// ---------------------------------------------------------------------------
__global__ void __launch_bounds__(256) prep(const float* __restrict__ x,
        const float* __restrict__ y,
        unsigned short* __restrict__ xh, unsigned short* __restrict__ xl,
        unsigned short* __restrict__ yh, unsigned short* __restrict__ yl,
        unsigned short* __restrict__ yT) {
    __shared__ unsigned short tile[64][66];
    const int n0 = blockIdx.x * 64, k0 = blockIdx.y * 64;
    const int t = threadIdx.x;
    if (blockIdx.z < 8) {
        const int b = blockIdx.z;
        const float* src = y + (size_t)b * KK * NN;
        unsigned short* dsth = yh + (size_t)b * KK * NN;
        unsigned short* dstl = yl + (size_t)b * KK * NN;
        unsigned short* dstT = yT + (size_t)b * NN * KK;
        #pragma unroll
        for (int i = 0; i < 4; ++i) {
            int idx = t + 256 * i;      // 0..1023 float4 units
            int r = idx >> 4;           // 0..63 (k)
            int c4 = (idx & 15) * 4;    // 0..60 (n)
            float4 v = *(const float4*)(src + (size_t)(k0 + r) * NN + n0 + c4);
            float a[4] = {v.x, v.y, v.z, v.w};
            unsigned short hb[4], lb[4];
            #pragma unroll
            for (int q = 0; q < 4; ++q) {
                __bf16 h = (__bf16)a[q];
                float hf = (float)h;
                __bf16 l = (__bf16)(a[q] - hf);
                hb[q] = __builtin_bit_cast(unsigned short, h);
                lb[q] = __builtin_bit_cast(unsigned short, l);
                tile[r][c4 + q] = hb[q];
            }
            size_t off = (size_t)(k0 + r) * NN + n0 + c4;
            *(ushort4*)(dsth + off) = make_ushort4(hb[0], hb[1], hb[2], hb[3]);
            *(ushort4*)(dstl + off) = make_ushort4(lb[0], lb[1], lb[2], lb[3]);
        }
        __syncthreads();
        #pragma unroll
        for (int i = 0; i < 16; ++i) {
            int idx = t + 256 * i;     // 0..4095
            int rn = idx >> 6;         // 0..63 (n)
            int ck = idx & 63;         // 0..63 (k)
            dstT[(size_t)(n0 + rn) * KK + k0 + ck] = tile[ck][rn];
        }
    } else {
        const int b = blockIdx.z - 8;
        const float* src = x + (size_t)b * CC * NN;
        unsigned short* dsth = xh + (size_t)b * CC * NN;
        unsigned short* dstl = xl + (size_t)b * CC * NN;
        #pragma unroll
        for (int i = 0; i < 4; ++i) {
            int idx = t + 256 * i;
            int r = idx >> 4;           // 0..63 (c)
            int c4 = (idx & 15) * 4;    // 0..60 (n)
            float4 v = *(const float4*)(src + (size_t)(k0 + r) * NN + n0 + c4);
            float a[4] = {v.x, v.y, v.z, v.w};
            unsigned short hb[4], lb[4];
            #pragma unroll
            for (int q = 0; q < 4; ++q) {
                __bf16 h = (__bf16)a[q];
                float hf = (float)h;
                __bf16 l = (__bf16)(a[q] - hf);
                hb[q] = __builtin_bit_cast(unsigned short, h);
                lb[q] = __builtin_bit_cast(unsigned short, l);
            }
            size_t off = (size_t)(k0 + r) * NN + n0 + c4;
            *(ushort4*)(dsth + off) = make_ushort4(hb[0], hb[1], hb[2], hb[3]);
            *(ushort4*)(dstl + off) = make_ushort4(lb[0], lb[1], lb[2], lb[3]);
        }
    }
}

// ---------------------------------------------------------------------------
// K1: energy[b][c][k] = sum_n x[b][c][n]*y[b][k][n], split-bf16 (3 MFMAs).
// 128x128 output tile, BK=64, split-N=4 (grid (4,4,32) — measured better than
// the XCD-swizzled 1D decode since the working set is L3-resident).
// Staging: global_load_lds width 16, linear LDS dest + XOR-swizzled source;
// ds_read_b128 fragments with the same swizzle (G21 both-sides involution).
// ---------------------------------------------------------------------------
__global__ void __launch_bounds__(256) energy_gemm(
        const unsigned short* __restrict__ xh, const unsigned short* __restrict__ xl,
        const unsigned short* __restrict__ yh, const unsigned short* __restrict__ yl,
        float* __restrict__ epart) {
    __shared__ __align__(16) uint8_t smem[4 * 16384];  // Ah, Al, Bh, Bl : [128][64] bf16
    const int ktile = blockIdx.x;        // 0..3  (key tiles, 128 each)
    const int ctile = blockIdx.y;        // 0..3  (query tiles, 128 each)
    const int b = blockIdx.z >> 2;
    const int quarter = blockIdx.z & 3;  // split-N quarter (1024 contraction cols)
    const int t = threadIdx.x;
    const int wave = t >> 6, lane = t & 63;

    const size_t rowB = (size_t)NN * 2;  // 8192 B per bf16 row
    const uint8_t* srcBase[4];
    srcBase[0] = (const uint8_t*)xh + ((size_t)b * CC + ctile * 128) * rowB + (size_t)quarter * 2048;
    srcBase[1] = (const uint8_t*)xl + ((size_t)b * CC + ctile * 128) * rowB + (size_t)quarter * 2048;
    srcBase[2] = (const uint8_t*)yh + ((size_t)b * KK + ktile * 128) * rowB + (size_t)quarter * 2048;
    srcBase[3] = (const uint8_t*)yl + ((size_t)b * KK + ktile * 128) * rowB + (size_t)quarter * 2048;

    f32x4 acc[4][4] = {};
    const int waveRow = wave >> 1, waveCol = wave & 1;

    for (int step = 0; step < 16; ++step) {
        const size_t colByte = (size_t)step * 128;
        #pragma unroll
        for (int i = 0; i < 16; ++i) {
            const int tile = i >> 2;                // compile-time after unroll
            const int lc = (i & 3) * 4 + wave;      // chunk 0..15 within tile
            const int u = lc * 64 + lane;           // 16B unit index in tile
            const int r = u >> 3;                   // row 0..127
            const int c3 = (u & 7) ^ (r & 7);       // inverse-swizzled source unit
            const uint8_t* src = srcBase[tile] + (size_t)r * rowB + colByte + c3 * 16;
            __builtin_amdgcn_global_load_lds((gbl_ptr_t)src,
                (lds_ptr_t)(smem + tile * 16384 + lc * 1024), 16, 0, 0);
        }
        __syncthreads();
        #pragma unroll
        for (int kf = 0; kf < 2; ++kf) {
            bf16x8 fah[4], fal[4], fbh[4], fbl[4];
            #pragma unroll
            for (int m = 0; m < 4; ++m) {
                int r = waveRow * 64 + m * 16 + (lane & 15);
                int c3 = (kf * 4 + (lane >> 4)) ^ (r & 7);
                fah[m] = *(const bf16x8*)(smem + 0 * 16384 + r * 128 + c3 * 16);
                fal[m] = *(const bf16x8*)(smem + 1 * 16384 + r * 128 + c3 * 16);
            }
            #pragma unroll
            for (int n = 0; n < 4; ++n) {
                int r = waveCol * 64 + n * 16 + (lane & 15);
                int c3 = (kf * 4 + (lane >> 4)) ^ (r & 7);
                fbh[n] = *(const bf16x8*)(smem + 2 * 16384 + r * 128 + c3 * 16);
                fbl[n] = *(const bf16x8*)(smem + 3 * 16384 + r * 128 + c3 * 16);
            }
            #pragma unroll
            for (int m = 0; m < 4; ++m)
            #pragma unroll
            for (int n = 0; n < 4; ++n) {
                acc[m][n] = __builtin_amdgcn_mfma_f32_16x16x32_bf16(fah[m], fbh[n], acc[m][n], 0, 0, 0);
                acc[m][n] = __builtin_amdgcn_mfma_f32_16x16x32_bf16(fah[m], fbl[n], acc[m][n], 0, 0, 0);
                acc[m][n] = __builtin_amdgcn_mfma_f32_16x16x32_bf16(fal[m], fbh[n], acc[m][n], 0, 0, 0);
            }
        }
        __syncthreads();
    }

    // C/D layout: col = lane&15, row = (lane>>4)*4 + reg  [m89-verified]
    float* eout = epart + (size_t)quarter * BB * CC * KK + (size_t)b * CC * KK;
    const int row0 = ctile * 128 + waveRow * 64;
    const int col0 = ktile * 128 + waveCol * 64;
    #pragma unroll
    for (int m = 0; m < 4; ++m)
    #pragma unroll
    for (int n = 0; n < 4; ++n)
    #pragma unroll
    for (int jj = 0; jj < 4; ++jj) {
        int rr = row0 + m * 16 + (lane >> 4) * 4 + jj;
        int cc2 = col0 + n * 16 + (lane & 15);
        eout[(size_t)rr * KK + cc2] = acc[m][n][jj];
    }
}

// ---------------------------------------------------------------------------
// K2: inverted softmax. softmax(max-e) == exp(min-e)/sum. One wave per row,
// vectorized f32x4 partial sums + ushort4 bf16 stores.
// ---------------------------------------------------------------------------
__global__ void __launch_bounds__(256) softmax_inv(
        const float* __restrict__ e, unsigned short* __restrict__ att) {
    const int t = threadIdx.x;
    const int wave = t >> 6, lane = t & 63;
    const int row = blockIdx.x * 4 + wave;   // 0..B*C-1
    const size_t Q4 = (size_t)BB * CC * KK / 4;   // quarter stride in float4s
    const f32x4* p = (const f32x4*)(e) + (size_t)row * (KK / 4);
    f32x4 v[2];
    float mn = 3.0e38f;
    #pragma unroll
    for (int i = 0; i < 2; ++i) {
        int c = lane + i * 64;               // 0..127 float4 units of the row
        v[i] = p[c] + p[Q4 + c] + p[2 * Q4 + c] + p[3 * Q4 + c];
        #pragma unroll
        for (int q = 0; q < 4; ++q) mn = fminf(mn, v[i][q]);
    }
    #pragma unroll
    for (int off = 32; off > 0; off >>= 1) mn = fminf(mn, __shfl_xor(mn, off));
    float s = 0.f;
    f32x4 pr[2];
    #pragma unroll
    for (int i = 0; i < 2; ++i)
    #pragma unroll
    for (int q = 0; q < 4; ++q) { pr[i][q] = __expf(mn - v[i][q]); s += pr[i][q]; }
    #pragma unroll
    for (int off = 32; off > 0; off >>= 1) s += __shfl_xor(s, off);
    float inv = 1.0f / s;
    ushort4* arow = (ushort4*)(att + (size_t)row * KK);
    #pragma unroll
    for (int i = 0; i < 2; ++i) {
        arow[lane + i * 64] = make_ushort4(
            bf16_bits(pr[i][0] * inv), bf16_bits(pr[i][1] * inv),
            bf16_bits(pr[i][2] * inv), bf16_bits(pr[i][3] * inv));
    }
}

// ---------------------------------------------------------------------------
// K3: out[b][c][n] = x[b][c][n] + scale * sum_k att[b][c][k]*yT[b][n][k].
// 128x128 tile, BK=64, 8 k-steps; same swizzled global_load_lds staging.
// 1D grid 1024, XCD = batch b -> yT/att b-slice L2-resident.
// ---------------------------------------------------------------------------
__global__ void __launch_bounds__(256) pv_residual(
        const unsigned short* __restrict__ att, const unsigned short* __restrict__ yT,
        const float* __restrict__ x, const float* __restrict__ scale,
        float* __restrict__ out) {
    __shared__ __align__(16) uint8_t smem[2 * 16384];   // A: att [128][64], B: yT [128][64]
    const int j = blockIdx.x;
    const int b = j & 7;                 // XCD = batch
    const int rem2 = j >> 3;             // 0..127
    const int ntile = rem2 & 31;         // 0..31
    const int ctile = rem2 >> 5;         // 0..3
    const int t = threadIdx.x;
    const int wave = t >> 6, lane = t & 63;
    const size_t rowB = (size_t)KK * 2;   // 1024 B
    const uint8_t* srcA = (const uint8_t*)att + ((size_t)b * CC + ctile * 128) * rowB;
    const uint8_t* srcB = (const uint8_t*)yT  + ((size_t)b * NN + ntile * 128) * rowB;

    f32x4 acc[4][4] = {};
    const int waveRow = wave >> 1, waveCol = wave & 1;

    for (int step = 0; step < 8; ++step) {
        const size_t colByte = (size_t)step * 128;
        #pragma unroll
        for (int i = 0; i < 8; ++i) {
            const uint8_t* base = (i < 4) ? srcA : srcB;  // compile-time per unrolled i
            const int tile = i >> 2;
            const int lc = (i & 3) * 4 + wave;            // 0..15
            const int u = lc * 64 + lane;
            const int r = u >> 3;                         // 0..127
            const int c3 = (u & 7) ^ (r & 7);
            const uint8_t* src = base + (size_t)r * rowB + colByte + c3 * 16;
            __builtin_amdgcn_global_load_lds((gbl_ptr_t)src,
                (lds_ptr_t)(smem + tile * 16384 + lc * 1024), 16, 0, 0);
        }
        __syncthreads();
        #pragma unroll
        for (int kf = 0; kf < 2; ++kf) {
            bf16x8 fa[4], fb[4];
            #pragma unroll
            for (int m = 0; m < 4; ++m) {
                int r = waveRow * 64 + m * 16 + (lane & 15);
                int c3 = (kf * 4 + (lane >> 4)) ^ (r & 7);
                fa[m] = *(const bf16x8*)(smem + r * 128 + c3 * 16);
            }
            #pragma unroll
            for (int n = 0; n < 4; ++n) {
                int r = waveCol * 64 + n * 16 + (lane & 15);
                int c3 = (kf * 4 + (lane >> 4)) ^ (r & 7);
                fb[n] = *(const bf16x8*)(smem + 16384 + r * 128 + c3 * 16);
            }
            #pragma unroll
            for (int m = 0; m < 4; ++m)
            #pragma unroll
            for (int n = 0; n < 4; ++n)
                acc[m][n] = __builtin_amdgcn_mfma_f32_16x16x32_bf16(fa[m], fb[n], acc[m][n], 0, 0, 0);
        }
        __syncthreads();
    }

    const float s = scale[0];
    const int row0 = ctile * 128 + waveRow * 64;
    const int col0 = ntile * 128 + waveCol * 64;
    #pragma unroll
    for (int m = 0; m < 4; ++m)
    #pragma unroll
    for (int n = 0; n < 4; ++n)
    #pragma unroll
    for (int jj = 0; jj < 4; ++jj) {
        int rr = row0 + m * 16 + (lane >> 4) * 4 + jj;
        int cc2 = col0 + n * 16 + (lane & 15);
        size_t idx = ((size_t)b * CC + rr) * NN + cc2;
        out[idx] = x[idx] + s * acc[m][n][jj];
    }
}

// ---------------------------------------------------------------------------
// Buffer plan (ws 132 MiB; d_out doubles as scratch):
//   ws[0,32M)    xh
//   ws[32M,64M)  yh
//   ws[64M,96M)  yl
//   ws[96M,128M) yT
//   ws[128M,132M) att
//   d_out[0,32M)  4 x 8 MiB energy partials  (dead after softmax_inv)
//   d_out[32M,64M) xl                        (dead after energy_gemm)
//   pv_residual finally overwrites all of d_out.
// ---------------------------------------------------------------------------
extern "C" void kernel_launch(void* const* d_in, const int* in_sizes, int n_in,
                              void* d_out, int out_size, void* d_ws, size_t ws_size,
                              hipStream_t stream) {
    const float* x = (const float*)d_in[0];
    const float* y = (const float*)d_in[1];
    const float* scale = (const float*)d_in[2];
    float* out = (float*)d_out;
    uint8_t* ws = (uint8_t*)d_ws;
    uint8_t* ob = (uint8_t*)d_out;
    const size_t MB = 1024 * 1024;
    unsigned short* xh = (unsigned short*)(ws + 0 * MB);
    unsigned short* yh = (unsigned short*)(ws + 32 * MB);
    unsigned short* yl = (unsigned short*)(ws + 64 * MB);
    unsigned short* yT = (unsigned short*)(ws + 96 * MB);
    unsigned short* att = (unsigned short*)(ws + 128 * MB);
    float* epart = (float*)(ob + 0 * MB);                  // d_out lower half
    unsigned short* xl = (unsigned short*)(ob + 32 * MB);  // d_out upper half

    prep<<<dim3(NN / 64, KK / 64, 16), 256, 0, stream>>>(x, y, xh, xl, yh, yl, yT);
    energy_gemm<<<dim3(4, 4, BB * 4), 256, 0, stream>>>(xh, xl, yh, yl, epart);
    softmax_inv<<<BB * CC / 4, 256, 0, stream>>>(epart, att);
    pv_residual<<<1024, 256, 0, stream>>>(att, yT, x, scale, out);
}